// Round 5
// baseline (1921.271 us; speedup 1.0000x reference)
//
#include <hip/hip_runtime.h>
#include <math.h>

#define NN 50000
#define MP 50048           // NN padded to multiple of 128
#define EE 800000
#define DD 256
#define HH 8
#define CC 32
#define EDIMK 16
#define LL 6
#define HID 1024
#define NEG 0.2f
#define LNEPS 1e-5f
#define NPARTS ((NN + 255) / 256)

using short8   = __attribute__((ext_vector_type(8))) short;
using ushort8  = __attribute__((ext_vector_type(8))) unsigned short;
using floatx4  = __attribute__((ext_vector_type(4))) float;

static __device__ __forceinline__ float4 ld4(const float* p) {
    return *reinterpret_cast<const float4*>(p);
}
static __device__ __forceinline__ void st4(float* p, float4 v) {
    *reinterpret_cast<float4*>(p) = v;
}
static __device__ __forceinline__ float b2f(unsigned short u) {
    union { unsigned int i; float f; } v; v.i = ((unsigned int)u) << 16; return v.f;
}
static __device__ __forceinline__ unsigned short f2b(float f) {
    union { float f; unsigned int i; } v; v.f = f;
    unsigned int r = (v.i + 0x7fffu + ((v.i >> 16) & 1u)) >> 16;
    return (unsigned short)r;
}
static __device__ __forceinline__ void gload_lds16(const ushort* g, ushort* l) {
    __builtin_amdgcn_global_load_lds((const __attribute__((address_space(1))) void*)g,
                                     (__attribute__((address_space(3))) void*)l, 16, 0, 0);
}

// ---- w_eh[k][h] = sum_c W_edge[k, h*32+c] * att_edge[h, c] ----
__global__ void k_weh(const float* __restrict__ W_edge, const float* __restrict__ att_edge,
                      float* __restrict__ w_eh) {
    int t = threadIdx.x;
    if (t < EDIMK * HH) {
        int k = t >> 3, h = t & 7;
        float s = 0.f;
        for (int c = 0; c < CC; ++c) s += W_edge[k * DD + h * CC + c] * att_edge[h * CC + c];
        w_eh[t] = s;
    }
}

// ---- degree count ----
__global__ void k_deg(const int* __restrict__ ei, int* __restrict__ deg) {
    int e = blockIdx.x * blockDim.x + threadIdx.x;
    if (e >= EE) return;
    atomicAdd(&deg[ei[EE + e]], 1);
}

// ---- 3-phase scan: deg -> rowptr (exclusive) ----
__global__ __launch_bounds__(256) void k_scan1(const int* __restrict__ deg,
                                               int* __restrict__ rowptr,
                                               int* __restrict__ part) {
    __shared__ int wsum[4];
    int tid = threadIdx.x, wid = tid >> 6, lane = tid & 63;
    int g = blockIdx.x * 256 + tid;
    int v = (g < NN) ? deg[g] : 0;
    int s = v;
#pragma unroll
    for (int off = 1; off < 64; off <<= 1) {
        int t = __shfl_up(s, off, 64);
        if (lane >= off) s += t;
    }
    if (lane == 63) wsum[wid] = s;
    __syncthreads();
    int woff = 0;
    for (int i = 0; i < wid; ++i) woff += wsum[i];
    s += woff;
    if (g < NN) rowptr[g + 1] = s;
    if (tid == 255) part[blockIdx.x] = s;
}
__global__ __launch_bounds__(256) void k_scan2(int* __restrict__ part) {
    __shared__ int wsum[4];
    int tid = threadIdx.x, wid = tid >> 6, lane = tid & 63;
    int v = (tid < NPARTS) ? part[tid] : 0;
    int s = v;
#pragma unroll
    for (int off = 1; off < 64; off <<= 1) {
        int t = __shfl_up(s, off, 64);
        if (lane >= off) s += t;
    }
    if (lane == 63) wsum[wid] = s;
    __syncthreads();
    int woff = 0;
    for (int i = 0; i < wid; ++i) woff += wsum[i];
    s += woff;
    if (tid < NPARTS) part[tid] = s - v;   // exclusive
}
__global__ __launch_bounds__(256) void k_scan3(int* __restrict__ rowptr,
                                               const int* __restrict__ part) {
    int g = blockIdx.x * 256 + threadIdx.x;
    if (g == 0) rowptr[0] = 0;
    if (g < NN) rowptr[g + 1] += part[blockIdx.x];
}

__global__ void k_scatter(const int* __restrict__ ei, const int* __restrict__ rowptr,
                          int* __restrict__ cursor, int* __restrict__ s_src,
                          int* __restrict__ perm) {
    int e = blockIdx.x * blockDim.x + threadIdx.x;
    if (e >= EE) return;
    int dst = ei[EE + e];
    int p = rowptr[dst] + atomicAdd(&cursor[dst], 1);
    s_src[p] = ei[e];
    perm[e] = p;
}

// ---- per-edge a_edge computed directly into CSR order ----
__global__ void k_edge_csr(const float* __restrict__ edge_attr, const int* __restrict__ perm,
                           const float* __restrict__ w_eh, float* __restrict__ ae_csr) {
    __shared__ float sw[EDIMK * HH];
    if (threadIdx.x < EDIMK * HH) sw[threadIdx.x] = w_eh[threadIdx.x];
    __syncthreads();
    int e = blockIdx.x * blockDim.x + threadIdx.x;
    if (e >= EE) return;
    float ea[EDIMK];
#pragma unroll
    for (int k4 = 0; k4 < EDIMK; k4 += 4) {
        float4 v = ld4(edge_attr + (size_t)e * EDIMK + k4);
        ea[k4] = v.x; ea[k4 + 1] = v.y; ea[k4 + 2] = v.z; ea[k4 + 3] = v.w;
    }
    int p = perm[e];
    float* out = ae_csr + (size_t)p * HH;
#pragma unroll
    for (int h = 0; h < HH; ++h) {
        float s = 0.f;
#pragma unroll
        for (int k = 0; k < EDIMK; ++k) s += ea[k] * sw[k * HH + h];
        out[h] = s;
    }
}

// ---- self-loop a_edge = mean of incoming ----
__global__ void k_selfmean(const int* __restrict__ rowptr, const float* __restrict__ ae_csr,
                           float* __restrict__ a_self) {
    int t = blockIdx.x * blockDim.x + threadIdx.x;
    if (t >= NN * HH) return;
    int n = t >> 3, h = t & 7;
    int k0 = rowptr[n], k1 = rowptr[n + 1];
    float s = 0.f;
    for (int k = k0; k < k1; ++k) s += ae_csr[(size_t)k * HH + h];
    int d = k1 - k0; if (d < 1) d = 1;
    a_self[t] = s / (float)d;
}

// ---- weight transpose + bf16 convert: dst[b][n][k] = src[b][k][n] ----
__global__ __launch_bounds__(1024) void k_trans(const float* __restrict__ src,
                                                ushort* __restrict__ dst, int K, int N) {
    __shared__ float s[32][33];
    const float* S = src + (size_t)blockIdx.z * K * N;
    ushort* D = dst + (size_t)blockIdx.z * K * N;
    int n0 = blockIdx.x * 32, k0 = blockIdx.y * 32;
    s[threadIdx.y][threadIdx.x] = S[(size_t)(k0 + threadIdx.y) * N + n0 + threadIdx.x];
    __syncthreads();
    D[(size_t)(n0 + threadIdx.y) * K + k0 + threadIdx.x] = f2b(s[threadIdx.x][threadIdx.y]);
}

// ---- m = x ; m_b = bf16(x) ----
__global__ void k_cvt(const float* __restrict__ x, float* __restrict__ m,
                      ushort* __restrict__ mb) {
    int t = blockIdx.x * blockDim.x + threadIdx.x;
    if (t >= NN * DD) return;
    float v = x[t];
    m[t] = v;
    mb[t] = f2b(v);
}

// ---- bf16 MFMA GEMM: C[M,Nc] = A[M,K] @ Bt[Nc,K]^T, 128x128 tile, BK=64 ----
// mode 1: bf16 out (no bias)
__global__ __launch_bounds__(256) void k_gemm_bf16(const ushort* __restrict__ A,
                                                   const ushort* __restrict__ Bt,
                                                   const float* __restrict__ bias,
                                                   void* __restrict__ Cout,
                                                   int Nc, int K, int mode) {
    __shared__ ushort As[128 * 64];
    __shared__ ushort Bs[128 * 64];
    int tid = threadIdx.x;
    int w = tid >> 6, lane = tid & 63;
    int tileM = blockIdx.y * 128, tileN = blockIdx.x * 128;
    const ushort* gA[4]; const ushort* gB[4];
    ushort* lA[4]; ushort* lB[4];
#pragma unroll
    for (int p = 0; p < 4; ++p) {
        int c = (p * 4 + w) * 64 + lane;
        int row = c >> 3, slot = c & 7;
        int gs = slot ^ (row & 7);
        gA[p] = A + (size_t)(tileM + row) * K + gs * 8;
        gB[p] = Bt + (size_t)(tileN + row) * K + gs * 8;
        lA[p] = As + (size_t)c * 8;
        lB[p] = Bs + (size_t)c * 8;
    }
    int wr = w >> 1, wc = w & 1;
    int fr = lane & 15, q = lane >> 4;
    floatx4 acc[4][4] = {};
    for (int k0 = 0; k0 < K; k0 += 64) {
        __syncthreads();
#pragma unroll
        for (int p = 0; p < 4; ++p) gload_lds16(gA[p] + k0, lA[p]);
#pragma unroll
        for (int p = 0; p < 4; ++p) gload_lds16(gB[p] + k0, lB[p]);
        __syncthreads();
#pragma unroll
        for (int kc = 0; kc < 2; ++kc) {
            int ps = ((kc * 4 + q) ^ (fr & 7)) * 8;
            short8 af[4], bf[4];
#pragma unroll
            for (int i = 0; i < 4; ++i)
                af[i] = *(const short8*)(As + (wr * 64 + i * 16 + fr) * 64 + ps);
#pragma unroll
            for (int j = 0; j < 4; ++j)
                bf[j] = *(const short8*)(Bs + (wc * 64 + j * 16 + fr) * 64 + ps);
#pragma unroll
            for (int i = 0; i < 4; ++i)
#pragma unroll
                for (int j = 0; j < 4; ++j)
                    acc[i][j] = __builtin_amdgcn_mfma_f32_16x16x32_bf16(af[i], bf[j], acc[i][j], 0, 0, 0);
        }
    }
    int rbase = tileM + wr * 64 + q * 4;
    int cbase = tileN + wc * 64 + fr;
#pragma unroll
    for (int j = 0; j < 4; ++j) {
        int col = cbase + j * 16;
        float bb = (mode != 1) ? bias[col] : 0.f;
#pragma unroll
        for (int i = 0; i < 4; ++i) {
            int row = rbase + i * 16;
#pragma unroll
            for (int r = 0; r < 4; ++r) {
                float v = acc[i][j][r] + bb;
                ((ushort*)Cout)[(size_t)(row + r) * Nc + col] = f2b(v);
            }
        }
    }
}

// ---- fully fused MLP: h = relu(A@W1+b1); out = LN(h@W2 + b2 + m) -> m, mb ----
// A = m_b (bf16). w1 [HID][DD], w2 [DD][HID] (both row = out-dim, col = k).
// 64-row tile per block; hidden streamed in 32-wide chunks, never hits global.
__global__ __launch_bounds__(256) void k_mlp(const ushort* __restrict__ A,
                                             const ushort* __restrict__ w1,
                                             const ushort* __restrict__ w2,
                                             const float* __restrict__ b1,
                                             const float* __restrict__ b2,
                                             const float* __restrict__ gma,
                                             const float* __restrict__ bta,
                                             float* __restrict__ m,
                                             ushort* __restrict__ mb) {
    __shared__ ushort As[64 * 256];
    __shared__ ushort W1s[32 * 256];
    __shared__ ushort W2s[256 * 32];
    __shared__ ushort Hs[64 * 32];
    __shared__ float redS[64][4];
    __shared__ float redQ[64][4];
    int tid = threadIdx.x;
    int w = tid >> 6, lane = tid & 63;
    int fr = lane & 15, q = lane >> 4;
    int tileM = blockIdx.x * 64;
    // stage A tile once (64 x 256 bf16), k-slot swizzled by row&7
#pragma unroll
    for (int p = 0; p < 8; ++p) {
        int c = p * 256 + tid;
        int row = c >> 5, sl = c & 31;
        int l = sl ^ (row & 7);
        gload_lds16(A + (size_t)(tileM + row) * DD + l * 8, As + (size_t)c * 8);
    }
    floatx4 acc2[4][4] = {};
    for (int ch = 0; ch < 32; ++ch) {
        // stage W1 chunk (32 hid-rows x 256 k) and W2 chunk (256 out-rows x 32 k)
#pragma unroll
        for (int p = 0; p < 4; ++p) {
            int c = p * 256 + tid;
            int row = c >> 5, sl = c & 31;
            int l = sl ^ (row & 7);
            gload_lds16(w1 + (size_t)(ch * 32 + row) * DD + l * 8, W1s + (size_t)c * 8);
        }
#pragma unroll
        for (int p = 0; p < 4; ++p) {
            int c = p * 256 + tid;
            int row = c >> 2, sl = c & 3;
            int l = sl ^ (row & 3);
            gload_lds16(w2 + (size_t)row * HID + ch * 32 + l * 8, W2s + (size_t)c * 8);
        }
        __syncthreads();
        // GEMM1: wave w -> rows w*16..+15, hidden cols 0..31, K=256
        floatx4 acc1[2] = {};
#pragma unroll
        for (int ks = 0; ks < 8; ++ks) {
            int ps = ((ks * 4 + q) ^ (fr & 7)) * 8;
            short8 af = *(const short8*)(As + (w * 16 + fr) * 256 + ps);
#pragma unroll
            for (int j = 0; j < 2; ++j) {
                short8 bf = *(const short8*)(W1s + (j * 16 + fr) * 256 + ps);
                acc1[j] = __builtin_amdgcn_mfma_f32_16x16x32_bf16(af, bf, acc1[j], 0, 0, 0);
            }
        }
        // bias + relu -> Hs (A-operand layout, slot swizzled by row&3)
#pragma unroll
        for (int j = 0; j < 2; ++j) {
            float bb = b1[ch * 32 + j * 16 + fr];
            int l = j * 2 + (fr >> 3);
#pragma unroll
            for (int r = 0; r < 4; ++r) {
                float v = acc1[j][r] + bb;
                v = v > 0.f ? v : 0.f;
                int row = w * 16 + q * 4 + r;
                Hs[row * 32 + ((l ^ r) * 8) + (fr & 7)] = f2b(v);
            }
        }
        __syncthreads();
        // GEMM2: all 64 rows x cols w*64..+63, K=32 (this chunk)
        {
            int ps2 = (q ^ (fr & 3)) * 8;
            short8 af2[4], bf2[4];
#pragma unroll
            for (int i = 0; i < 4; ++i)
                af2[i] = *(const short8*)(Hs + (i * 16 + fr) * 32 + ps2);
#pragma unroll
            for (int j = 0; j < 4; ++j)
                bf2[j] = *(const short8*)(W2s + (w * 64 + j * 16 + fr) * 32 + ps2);
#pragma unroll
            for (int i = 0; i < 4; ++i)
#pragma unroll
                for (int j = 0; j < 4; ++j)
                    acc2[i][j] = __builtin_amdgcn_mfma_f32_16x16x32_bf16(af2[i], bf2[j], acc2[i][j], 0, 0, 0);
        }
        __syncthreads();
    }
    // epilogue: bias + residual + per-row LN over 256 cols
    int colb = w * 64 + fr;
    float bw[4], gw[4], btw[4];
#pragma unroll
    for (int j = 0; j < 4; ++j) {
        bw[j] = b2[colb + j * 16];
        gw[j] = gma[colb + j * 16];
        btw[j] = bta[colb + j * 16];
    }
#pragma unroll
    for (int i = 0; i < 4; ++i) {
#pragma unroll
        for (int rr = 0; rr < 4; ++rr) {
            int lrow = i * 16 + q * 4 + rr;
            int grow = tileM + lrow;
            bool valid = grow < NN;
            float s = 0.f, s2 = 0.f;
#pragma unroll
            for (int j = 0; j < 4; ++j) {
                float rres = valid ? m[(size_t)grow * DD + colb + j * 16] : 0.f;
                float gv = acc2[i][j][rr] + bw[j] + rres;
                acc2[i][j][rr] = gv;
                s += gv; s2 += gv * gv;
            }
#pragma unroll
            for (int msk = 1; msk < 16; msk <<= 1) {
                s += __shfl_xor(s, msk, 16);
                s2 += __shfl_xor(s2, msk, 16);
            }
            if (fr == 0) { redS[lrow][w] = s; redQ[lrow][w] = s2; }
        }
    }
    __syncthreads();
#pragma unroll
    for (int i = 0; i < 4; ++i) {
#pragma unroll
        for (int rr = 0; rr < 4; ++rr) {
            int lrow = i * 16 + q * 4 + rr;
            int grow = tileM + lrow;
            if (grow >= NN) continue;
            float su = redS[lrow][0] + redS[lrow][1] + redS[lrow][2] + redS[lrow][3];
            float sq = redQ[lrow][0] + redQ[lrow][1] + redQ[lrow][2] + redQ[lrow][3];
            float mu = su * (1.0f / DD);
            float var = sq * (1.0f / DD) - mu * mu;
            float rs = rsqrtf(var + LNEPS);
#pragma unroll
            for (int j = 0; j < 4; ++j) {
                float v = (acc2[i][j][rr] - mu) * rs * gw[j] + btw[j];
                size_t idx = (size_t)grow * DD + colb + j * 16;
                m[idx] = v;
                mb[idx] = f2b(v);
            }
        }
    }
}

// ---- a_src/a_dst from bf16 x_proj ----
__global__ void k_srcdst(const ushort* __restrict__ xb, const float* __restrict__ att_src,
                         const float* __restrict__ att_dst, float* __restrict__ a_src,
                         float* __restrict__ a_dst) {
    __shared__ float ss[DD], sd[DD];
    int tid = threadIdx.x;
    if (tid < DD) { ss[tid] = att_src[tid]; sd[tid] = att_dst[tid]; }
    __syncthreads();
    int t = blockIdx.x * blockDim.x + tid;
    if (t >= NN * HH) return;
    int n = t >> 3, h = t & 7;
    const ushort* xp = xb + (size_t)n * DD + h * CC;
    float s1 = 0.f, s2 = 0.f;
#pragma unroll
    for (int c = 0; c < CC; c += 4) {
        ushort4 u = *(const ushort4*)(xp + c);
        float vx = b2f(u.x), vy = b2f(u.y), vz = b2f(u.z), vw = b2f(u.w);
        int b = h * CC + c;
        s1 += vx * ss[b] + vy * ss[b + 1] + vz * ss[b + 2] + vw * ss[b + 3];
        s2 += vx * sd[b] + vy * sd[b + 1] + vz * sd[b + 2] + vw * sd[b + 3];
    }
    a_src[t] = s1;
    a_dst[t] = s2;
}

// ---- fused softmax-aggregate + bias + residual + LN1 : 2 nodes/wave, 4-edge unroll ----
__global__ __launch_bounds__(256) void k_agg(const ushort* __restrict__ xb,
                                             const float* __restrict__ a_src,
                                             const float* __restrict__ a_dst,
                                             const float* __restrict__ a_self,
                                             const int* __restrict__ rowptr,
                                             const int* __restrict__ s_src,
                                             const float* __restrict__ ae_csr,
                                             const float* __restrict__ bias,
                                             const float* __restrict__ gma,
                                             const float* __restrict__ bta,
                                             float* __restrict__ m,
                                             ushort* __restrict__ mb) {
    int wid = (blockIdx.x * blockDim.x + threadIdx.x) >> 6;
    int lane = threadIdx.x & 63;
    int n = wid * 2 + (lane >> 5);
    if (n >= NN) return;
    int hl = lane & 31, h = hl >> 2, c8 = hl * 8;
    float adn = a_dst[n * HH + h];
    float al0 = a_src[n * HH + h] + adn + a_self[n * HH + h];
    al0 = al0 > 0.f ? al0 : NEG * al0;
    float w0 = __expf(al0);
    ushort8 xs = *(const ushort8*)(xb + (size_t)n * DD + c8);
    float acc[8];
#pragma unroll
    for (int i = 0; i < 8; ++i) acc[i] = w0 * b2f(xs[i]);
    float den = w0;
    int k = rowptr[n], k1 = rowptr[n + 1];
    for (; k + 3 < k1; k += 4) {
        int s0 = s_src[k], s1 = s_src[k + 1], s2 = s_src[k + 2], s3 = s_src[k + 3];
        float e0 = ae_csr[(size_t)k * HH + h];
        float e1 = ae_csr[(size_t)(k + 1) * HH + h];
        float e2 = ae_csr[(size_t)(k + 2) * HH + h];
        float e3 = ae_csr[(size_t)(k + 3) * HH + h];
        float t0 = a_src[(size_t)s0 * HH + h] + adn + e0;
        float t1 = a_src[(size_t)s1 * HH + h] + adn + e1;
        float t2 = a_src[(size_t)s2 * HH + h] + adn + e2;
        float t3 = a_src[(size_t)s3 * HH + h] + adn + e3;
        ushort8 v0 = *(const ushort8*)(xb + (size_t)s0 * DD + c8);
        ushort8 v1 = *(const ushort8*)(xb + (size_t)s1 * DD + c8);
        ushort8 v2 = *(const ushort8*)(xb + (size_t)s2 * DD + c8);
        ushort8 v3 = *(const ushort8*)(xb + (size_t)s3 * DD + c8);
        t0 = t0 > 0.f ? t0 : NEG * t0;
        t1 = t1 > 0.f ? t1 : NEG * t1;
        t2 = t2 > 0.f ? t2 : NEG * t2;
        t3 = t3 > 0.f ? t3 : NEG * t3;
        float wv0 = __expf(t0), wv1 = __expf(t1), wv2 = __expf(t2), wv3 = __expf(t3);
        den += (wv0 + wv1) + (wv2 + wv3);
#pragma unroll
        for (int i = 0; i < 8; ++i)
            acc[i] += (wv0 * b2f(v0[i]) + wv1 * b2f(v1[i])) + (wv2 * b2f(v2[i]) + wv3 * b2f(v3[i]));
    }
    for (; k < k1; ++k) {
        int s0 = s_src[k];
        float t0 = a_src[(size_t)s0 * HH + h] + adn + ae_csr[(size_t)k * HH + h];
        t0 = t0 > 0.f ? t0 : NEG * t0;
        float wv0 = __expf(t0);
        ushort8 v0 = *(const ushort8*)(xb + (size_t)s0 * DD + c8);
        den += wv0;
#pragma unroll
        for (int i = 0; i < 8; ++i) acc[i] += wv0 * b2f(v0[i]);
    }
    float inv = 1.f / den;
    size_t base = (size_t)n * DD + c8;
    float4 mr0 = ld4(m + base), mr1 = ld4(m + base + 4);
    float4 b0 = ld4(bias + c8), b1 = ld4(bias + c8 + 4);
    float g[8];
    g[0] = acc[0] * inv + b0.x + mr0.x; g[1] = acc[1] * inv + b0.y + mr0.y;
    g[2] = acc[2] * inv + b0.z + mr0.z; g[3] = acc[3] * inv + b0.w + mr0.w;
    g[4] = acc[4] * inv + b1.x + mr1.x; g[5] = acc[5] * inv + b1.y + mr1.y;
    g[6] = acc[6] * inv + b1.z + mr1.z; g[7] = acc[7] * inv + b1.w + mr1.w;
    float s = 0.f;
#pragma unroll
    for (int i = 0; i < 8; ++i) s += g[i];
#pragma unroll
    for (int off = 16; off; off >>= 1) s += __shfl_xor(s, off, 64);
    float mu = s * (1.0f / DD);
    float qv = 0.f;
#pragma unroll
    for (int i = 0; i < 8; ++i) { g[i] -= mu; qv += g[i] * g[i]; }
#pragma unroll
    for (int off = 16; off; off >>= 1) qv += __shfl_xor(qv, off, 64);
    float rs = rsqrtf(qv * (1.0f / DD) + LNEPS);
    float4 g0 = ld4(gma + c8), g1 = ld4(gma + c8 + 4);
    float4 bb0 = ld4(bta + c8), bb1 = ld4(bta + c8 + 4);
    float o[8];
    o[0] = g[0] * rs * g0.x + bb0.x; o[1] = g[1] * rs * g0.y + bb0.y;
    o[2] = g[2] * rs * g0.z + bb0.z; o[3] = g[3] * rs * g0.w + bb0.w;
    o[4] = g[4] * rs * g1.x + bb1.x; o[5] = g[5] * rs * g1.y + bb1.y;
    o[6] = g[6] * rs * g1.z + bb1.z; o[7] = g[7] * rs * g1.w + bb1.w;
    st4(m + base, make_float4(o[0], o[1], o[2], o[3]));
    st4(m + base + 4, make_float4(o[4], o[5], o[6], o[7]));
    ushort8 ob;
#pragma unroll
    for (int i = 0; i < 8; ++i) ob[i] = f2b(o[i]);
    *reinterpret_cast<ushort8*>(mb + base) = ob;
}

extern "C" void kernel_launch(void* const* d_in, const int* in_sizes, int n_in,
                              void* d_out, int out_size, void* d_ws, size_t ws_size,
                              hipStream_t stream) {
    const float* x        = (const float*)d_in[0];
    const int*   ei       = (const int*)d_in[1];
    const float* edge_attr= (const float*)d_in[2];
    const float* W        = (const float*)d_in[3];
    const float* att_src  = (const float*)d_in[4];
    const float* att_dst  = (const float*)d_in[5];
    const float* att_edge = (const float*)d_in[6];
    const float* W_edge   = (const float*)d_in[7];
    const float* bias     = (const float*)d_in[8];
    const float* ffn_w1   = (const float*)d_in[9];
    const float* ffn_b1   = (const float*)d_in[10];
    const float* ffn_w2   = (const float*)d_in[11];
    const float* ffn_b2   = (const float*)d_in[12];
    const float* ln1_g    = (const float*)d_in[13];
    const float* ln1_b    = (const float*)d_in[14];
    const float* ln2_g    = (const float*)d_in[15];
    const float* ln2_b    = (const float*)d_in[16];
    float* m = (float*)d_out;

    char* wp = (char*)d_ws;
    auto alloc = [&](size_t bytes) -> char* {
        char* p = wp;
        wp += (bytes + 255) & ~(size_t)255;
        return p;
    };
    float*  ae_csr = (float*)alloc((size_t)EE * HH * 4);
    float*  a_self = (float*)alloc((size_t)NN * HH * 4);
    float*  a_src  = (float*)alloc((size_t)NN * HH * 4);
    float*  a_dst  = (float*)alloc((size_t)NN * HH * 4);
    int*    deg    = (int*)alloc((size_t)NN * 4);
    int*    rowptr = (int*)alloc((size_t)(NN + 1) * 4);
    int*    cursor = (int*)alloc((size_t)NN * 4);
    int*    part   = (int*)alloc((size_t)NPARTS * 4);
    int*    s_src  = (int*)alloc((size_t)EE * 4);
    int*    perm   = (int*)alloc((size_t)EE * 4);
    float*  w_eh   = (float*)alloc((size_t)EDIMK * HH * 4);
    ushort* Wt     = (ushort*)alloc((size_t)DD * DD * 2);
    ushort* w1t    = (ushort*)alloc((size_t)LL * DD * HID * 2);
    ushort* w2t    = (ushort*)alloc((size_t)LL * HID * DD * 2);
    ushort* xprojb = (ushort*)alloc((size_t)MP * DD * 2);
    ushort* m_b    = (ushort*)alloc((size_t)MP * DD * 2);

    hipMemsetAsync(deg, 0, (size_t)NN * 4, stream);
    hipMemsetAsync(cursor, 0, (size_t)NN * 4, stream);

    // layer-invariant precompute
    k_weh<<<1, 128, 0, stream>>>(W_edge, att_edge, w_eh);
    k_deg<<<(EE + 255) / 256, 256, 0, stream>>>(ei, deg);
    k_scan1<<<NPARTS, 256, 0, stream>>>(deg, rowptr, part);
    k_scan2<<<1, 256, 0, stream>>>(part);
    k_scan3<<<NPARTS, 256, 0, stream>>>(rowptr, part);
    k_scatter<<<(EE + 255) / 256, 256, 0, stream>>>(ei, rowptr, cursor, s_src, perm);
    k_edge_csr<<<(EE + 255) / 256, 256, 0, stream>>>(edge_attr, perm, w_eh, ae_csr);
    k_selfmean<<<(NN * HH + 255) / 256, 256, 0, stream>>>(rowptr, ae_csr, a_self);
    // weights -> bf16 transposed
    k_trans<<<dim3(DD / 32, DD / 32, 1), dim3(32, 32), 0, stream>>>(W, Wt, DD, DD);
    k_trans<<<dim3(HID / 32, DD / 32, LL), dim3(32, 32), 0, stream>>>(ffn_w1, w1t, DD, HID);
    k_trans<<<dim3(DD / 32, HID / 32, LL), dim3(32, 32), 0, stream>>>(ffn_w2, w2t, HID, DD);
    // m = x, m_b = bf16(x)
    k_cvt<<<(NN * DD + 255) / 256, 256, 0, stream>>>(x, m, m_b);

    for (int i = 0; i < LL; ++i) {
        k_gemm_bf16<<<dim3(DD / 128, MP / 128), 256, 0, stream>>>(m_b, Wt, nullptr, xprojb, DD, DD, 1);
        k_srcdst<<<(NN * HH + 255) / 256, 256, 0, stream>>>(xprojb, att_src, att_dst, a_src, a_dst);
        k_agg<<<((NN + 1) / 2 * 64 + 255) / 256, 256, 0, stream>>>(xprojb, a_src, a_dst, a_self,
                                                                   rowptr, s_src, ae_csr, bias,
                                                                   ln1_g + i * DD, ln1_b + i * DD, m, m_b);
        k_mlp<<<MP / 64, 256, 0, stream>>>(m_b, w1t + (size_t)i * DD * HID,
                                           w2t + (size_t)i * HID * DD,
                                           ffn_b1 + (size_t)i * HID, ffn_b2 + (size_t)i * DD,
                                           ln2_g + i * DD, ln2_b + i * DD, m, m_b);
    }
}